// Round 9
// baseline (1150.982 us; speedup 1.0000x reference)
//
#include <hip/hip_runtime.h>
#include <hip/hip_bf16.h>

typedef __hip_bfloat16 bf16;
typedef __attribute__((ext_vector_type(8))) short short8;
typedef __attribute__((ext_vector_type(4))) float floatx4;

#define B_    16
#define L_    64
#define N_    1024
#define HANDD 99
#define Jn    21
#define HID   512
#define NLAY  4
#define NHEAD 8
#define DHEAD 64
#define CATD  2273
#define CATP  2304
#define S_    128
#define T_    2048

// float workspace offsets
#define F_X     16
#define F_QKV   1048592
#define F_TMP   6291472
#define F_H     7340048
#define WB_F    8388624
// ushort offsets from wb
#define W_FCL   0
#define W_FCR   1179648
#define W_QKV   2359296
#define W_WO    5505024
#define W_W1    6553600
#define W_W2    10747904
#define U_CATL  14942208
#define U_CATR  17301504
#define U_XB    19660800
#define U_AOB   20709376
#define U_HB    21757952
#define W_OUT   22806528
#define U_FFB   U_CATL   // alias: cat buffers dead after fc

static __device__ __forceinline__ float b2f(bf16 x) { return __bfloat162float(x); }
static __device__ __forceinline__ float ldin(const void* p, size_t i, int isf32) {
    return isf32 ? ((const float*)p)[i] : b2f(((const bf16*)p)[i]);
}
static __device__ __forceinline__ unsigned short f2bf(float f) {
    unsigned int u = __float_as_uint(f);
    unsigned int r = (u + 0x7fffu + ((u >> 16) & 1u)) >> 16;
    return (unsigned short)r;
}

__global__ __launch_bounds__(256) void detect_kernel(const void* mc, int* flag)
{
    __shared__ int sbad;
    int tid = threadIdx.x;
    if (tid == 0) sbad = 0;
    __syncthreads();
    int bad = 0;
    for (int i = tid; i < 16384; i += 256) {
        float v = b2f(((const bf16*)mc)[i]);
        if (!(v >= -0.02f && v <= 1.02f)) bad = 1;
    }
    if (bad) atomicOr(&sbad, 1);
    __syncthreads();
    if (tid == 0) flag[0] = sbad ? 1 : 0;
}

// weight transpose+convert: src [K][NnBound] -> dst [N][Kpad] bf16, zero pad
__global__ __launch_bounds__(256) void wtrans_kernel(
    const void* __restrict__ src, size_t src_layer, int K, int Nn, int NnBound,
    int Kpad, unsigned short* __restrict__ dst, size_t dst_layer,
    const int* __restrict__ dtf)
{
    int isf32 = dtf[0];
    __shared__ float tile[64][65];
    int lay = blockIdx.z;
    size_t soff = (size_t)lay * src_layer;
    size_t doff = (size_t)lay * dst_layer;
    int n0 = blockIdx.x * 64, k0 = blockIdx.y * 64;
    int a = threadIdx.x & 63, bq = threadIdx.x >> 6;
    for (int r = bq; r < 64; r += 4) {
        int k = k0 + r;
        int n = n0 + a;
        float v = (k < K && n < NnBound) ? ldin(src, soff + (size_t)k * Nn + n, isf32) : 0.f;
        tile[r][a] = v;
    }
    __syncthreads();
    for (int r = bq; r < 64; r += 4) {
        dst[doff + (size_t)(n0 + r) * Kpad + k0 + a] = f2bf(tile[a][r]);
    }
}

// fused: rot6d->R, pc transform (LDS), pcn, NN-contact attention, both hands'
// bf16 feature rows. grid B*L blocks.
__global__ __launch_bounds__(256) void pctcat_kernel(
    const void* __restrict__ x_l, const void* __restrict__ j_l,
    const void* __restrict__ x_r, const void* __restrict__ j_r,
    const void* __restrict__ mc, const void* __restrict__ x_obj,
    const void* __restrict__ pc, unsigned short* __restrict__ cat_l,
    unsigned short* __restrict__ cat_r, const int* __restrict__ dtf)
{
    __shared__ float pcl[N_ * 3];
    __shared__ float pcnl[N_];
    int isf32 = dtf[0];
    int bl = blockIdx.x;
    int b  = bl >> 6;
    int tid = threadIdx.x;

    size_t xo = (size_t)bl * 10;
    float t0 = ldin(x_obj, xo+0, isf32), t1 = ldin(x_obj, xo+1, isf32), t2 = ldin(x_obj, xo+2, isf32);
    float a1x = ldin(x_obj, xo+3, isf32), a1y = ldin(x_obj, xo+4, isf32), a1z = ldin(x_obj, xo+5, isf32);
    float a2x = ldin(x_obj, xo+6, isf32), a2y = ldin(x_obj, xo+7, isf32), a2z = ldin(x_obj, xo+8, isf32);
    float n1 = sqrtf(a1x*a1x + a1y*a1y + a1z*a1z);
    float b1x = a1x / n1, b1y = a1y / n1, b1z = a1z / n1;
    float d = b1x*a2x + b1y*a2y + b1z*a2z;
    float c2x = a2x - d*b1x, c2y = a2y - d*b1y, c2z = a2z - d*b1z;
    float n2 = sqrtf(c2x*c2x + c2y*c2y + c2z*c2z);
    float b2x = c2x / n2, b2y = c2y / n2, b2z = c2z / n2;
    float b3x = b1y*b2z - b1z*b2y;
    float b3y = b1z*b2x - b1x*b2z;
    float b3z = b1x*b2y - b1y*b2x;

    size_t pcb = (size_t)b * N_ * 3;
    for (int n = tid; n < N_; n += 256) {
        float p0 = ldin(pc, pcb + n*3+0, isf32);
        float p1 = ldin(pc, pcb + n*3+1, isf32);
        float p2 = ldin(pc, pcb + n*3+2, isf32);
        float q0 = b1x*p0 + b2x*p1 + b3x*p2 + t0;
        float q1 = b1y*p0 + b2y*p1 + b3y*p2 + t1;
        float q2 = b1z*p0 + b2z*p1 + b3z*p2 + t2;
        pcl[n*3+0] = q0; pcl[n*3+1] = q1; pcl[n*3+2] = q2;
        pcnl[n] = sqrtf(q0*q0 + q1*q1 + q2*q2);
    }
    __syncthreads();

    // feature rows (both hands)
    #pragma unroll
    for (int hand = 0; hand < 2; hand++) {
        const void* xh = hand ? x_r : x_l;
        const void* jh = hand ? j_r : j_l;
        unsigned short* row = (hand ? cat_r : cat_l) + (size_t)bl * CATP;
        for (int c = tid; c < HANDD; c += 256)  row[c]        = f2bf(ldin(xh, (size_t)bl*HANDD + c, isf32));
        for (int c = tid; c < 63;    c += 256)  row[99 + c]   = f2bf(ldin(jh, (size_t)bl*63 + c, isf32));
        for (int c = tid; c < N_;    c += 256)  row[162 + c]  = f2bf(ldin(mc, (size_t)b*N_ + c, isf32));
        for (int c = tid; c < N_;    c += 256)  row[1186 + c] = f2bf(pcnl[c]);
        for (int c = CATD + tid; c < CATP; c += 256) row[c] = 0;
    }

    int wave = tid >> 6, lane = tid & 63;
    for (int t = wave; t < 2 * Jn; t += 4) {
        int hand = t / Jn, j = t - hand * Jn;
        const void* jh = hand ? j_r : j_l;
        unsigned short* row = (hand ? cat_r : cat_l) + (size_t)bl * CATP;
        float jx = ldin(jh, (size_t)bl*63 + j*3 + 0, isf32);
        float jy = ldin(jh, (size_t)bl*63 + j*3 + 1, isf32);
        float jz = ldin(jh, (size_t)bl*63 + j*3 + 2, isf32);
        float jj = jx*jx + jy*jy + jz*jz;
        float best = 3.4e38f; int bidx = 0x7fffffff;
        for (int n = lane; n < N_; n += 64) {
            float p0 = pcl[n*3+0], p1 = pcl[n*3+1], p2 = pcl[n*3+2];
            float d2 = jj + (p0*p0 + p1*p1 + p2*p2) - 2.f*(jx*p0 + jy*p1 + jz*p2);
            if (d2 < best) { best = d2; bidx = n; }
        }
        for (int off = 32; off; off >>= 1) {
            float ob = __shfl_down(best, off, 64);
            int   oi = __shfl_down(bidx, off, 64);
            if (ob < best || (ob == best && oi < bidx)) { best = ob; bidx = oi; }
        }
        bidx = __shfl(bidx, 0, 64);
        if (lane < 3) {
            float jc = (lane == 0) ? jx : ((lane == 1) ? jy : jz);
            float cc = pcl[bidx*3 + lane];
            float dd = jc - cc;
            row[2210 + j*3 + lane] = f2bf(expf(-50.f * dd * dd));
        }
    }
}

// K-split MFMA GEMM: one 64x64 tile per block, 4 waves each take K/4,
// LDS tree-reduce. rowmap: 0 plain, 1/2 fc scatter + fused PE, 3 out-proj
// parity store. halfgrid: blocks >= halfgrid use Ab2/wtoff2/bias2 (rowmap 2).
#define RSTR 68

__global__ __launch_bounds__(256) void gemm_ks(
    const unsigned short* __restrict__ Ab, const unsigned short* __restrict__ Ab2,
    int K,
    const unsigned short* __restrict__ Wt, size_t wtoff, size_t wtoff2, int halfgrid,
    int Nn,
    const void* __restrict__ bias, const void* __restrict__ bias2, size_t boff,
    const float* __restrict__ resid,
    float* __restrict__ Df, unsigned short* __restrict__ Db,
    int relu, int rowmap, int tilesN, const int* __restrict__ dtf)
{
    __shared__ float red[4][64 * RSTR];
    int blk = blockIdx.x;
    if (halfgrid && blk >= halfgrid) {
        blk -= halfgrid; Ab = Ab2; wtoff = wtoff2; bias = bias2; rowmap = 2;
    }
    int tid = threadIdx.x;
    int wave = tid >> 6, lane = tid & 63;
    int quad = lane >> 4, l16 = lane & 15;
    int tm = blk / tilesN, tn = blk - tm * tilesN;
    int row0 = tm << 6, col0 = tn << 6;
    int Ks = K >> 2;
    int ks0 = wave * Ks;

    const unsigned short* Ap = Ab + (size_t)(row0 + l16) * K + ks0 + quad * 8;
    const unsigned short* Bp = Wt + wtoff + (size_t)(col0 + l16) * K + ks0 + quad * 8;
    size_t astep = (size_t)16 * K;

    floatx4 acc[4][4];
    #pragma unroll
    for (int i = 0; i < 4; i++)
        #pragma unroll
        for (int j = 0; j < 4; j++)
            acc[i][j] = (floatx4){0.f, 0.f, 0.f, 0.f};

    for (int k = 0; k < Ks; k += 32) {
        short8 af[4], bf[4];
        #pragma unroll
        for (int i = 0; i < 4; i++) {
            af[i] = *(const short8*)(Ap + i * astep + k);
            bf[i] = *(const short8*)(Bp + i * astep + k);
        }
        #pragma unroll
        for (int mi = 0; mi < 4; mi++)
            #pragma unroll
            for (int ni = 0; ni < 4; ni++)
                acc[mi][ni] = __builtin_amdgcn_mfma_f32_16x16x32_bf16(
                    af[mi], bf[ni], acc[mi][ni], 0, 0, 0);
    }

    #pragma unroll
    for (int mi = 0; mi < 4; mi++)
        #pragma unroll
        for (int ni = 0; ni < 4; ni++)
            #pragma unroll
            for (int reg = 0; reg < 4; reg++) {
                int r = mi * 16 + quad * 4 + reg;
                int c = ni * 16 + l16;
                red[wave][r * RSTR + c] = acc[mi][ni][reg];
            }
    __syncthreads();

    int isf32 = dtf[0];
    int cc = tid & 63;
    int c = col0 + cc;
    float bv;
    if (rowmap == 3)
        bv = (c < HANDD) ? ldin(bias, c, isf32)
           : ((c < 2 * HANDD) ? ldin(bias2, c - HANDD, isf32) : 0.f);
    else
        bv = bias ? ldin(bias, boff + c, isf32) : 0.f;
    float pe_div = 0.f, pa = 0.f;
    if (rowmap == 1 || rowmap == 2) {
        int ci = c & ~1;
        pe_div = expf((float)ci * (-logf(10000.f) / (float)HID));
        int hand = rowmap - 1;
        pa = (c & 1) ? cosf((float)hand * pe_div) : sinf((float)hand * pe_div);
    }
    int rbase = tid >> 6;
    #pragma unroll
    for (int j = 0; j < 16; j++) {
        int rr = rbase + (j << 2);
        int idx = rr * RSTR + cc;
        float v = red[0][idx] + red[1][idx] + red[2][idx] + red[3][idx] + bv;
        int r = row0 + rr;
        if (resid) v += resid[(size_t)r * Nn + c];
        if (relu)  v = fmaxf(v, 0.f);
        if (rowmap == 3) {
            int hand = r & 1;
            int l = (r >> 1) & 63, bb = r >> 7;
            if (hand == 0 && c < HANDD) {
                size_t oi = ((size_t)bb * 64 + l) * HANDD + c;
                if (isf32) ((float*)Df)[oi] = v;
                else       ((bf16*)Df)[oi]  = __float2bfloat16(v);
            } else if (hand == 1 && c >= HANDD && c < 2 * HANDD) {
                size_t oi = (size_t)B_ * L_ * HANDD + ((size_t)bb * 64 + l) * HANDD + (c - HANDD);
                if (isf32) ((float*)Df)[oi] = v;
                else       ((bf16*)Df)[oi]  = __float2bfloat16(v);
            }
        } else {
            int orow = r;
            if (rowmap) {
                int bb = r >> 6, ll = r & 63;
                orow = bb * S_ + 2 * ll + (rowmap - 1);
                float pf = (c & 1) ? cosf((float)ll * pe_div) : sinf((float)ll * pe_div);
                v += pf + pa;
            }
            if (Df) Df[(size_t)orow * Nn + c] = v;
            if (Db) Db[(size_t)orow * Nn + c] = f2bf(v);
        }
    }
}

// fused attention: scores + softmax + PV in one kernel. grid B*NH.
__global__ __launch_bounds__(256) void attn_fused(
    const float* __restrict__ qkv, unsigned short* __restrict__ aob)
{
    int bh = blockIdx.x;
    int b = bh >> 3, h = bh & 7;
    __shared__ float Ks[S_][DHEAD + 1];
    __shared__ float Vs[S_][DHEAD + 1];
    __shared__ float Pr[4][S_];
    int tid = threadIdx.x;
    for (int i = tid; i < S_ * DHEAD; i += 256) {
        int r = i >> 6, dd = i & 63;
        size_t base = (size_t)(b * S_ + r) * 1536 + h * DHEAD + dd;
        Ks[r][dd] = qkv[base + 512];
        Vs[r][dd] = qkv[base + 1024];
    }
    __syncthreads();
    int wave = tid >> 6, lane = tid & 63;
    for (int r = wave; r < S_; r += 4) {
        const float* qrow = &qkv[(size_t)(b * S_ + r) * 1536 + h * DHEAD];
        float s0 = 0.f, s1 = 0.f;
        #pragma unroll 8
        for (int dd = 0; dd < DHEAD; dd++) {
            float qd = qrow[dd];
            s0 += qd * Ks[lane][dd];
            s1 += qd * Ks[lane + 64][dd];
        }
        s0 *= 0.125f; s1 *= 0.125f;
        float m = fmaxf(s0, s1);
        for (int off = 32; off; off >>= 1) m = fmaxf(m, __shfl_down(m, off, 64));
        m = __shfl(m, 0, 64);
        float e0 = expf(s0 - m), e1 = expf(s1 - m);
        float sum = e0 + e1;
        for (int off = 32; off; off >>= 1) sum += __shfl_down(sum, off, 64);
        sum = __shfl(sum, 0, 64);
        float inv = 1.f / sum;
        Pr[wave][lane]      = e0 * inv;
        Pr[wave][lane + 64] = e1 * inv;
        float acc = 0.f;
        #pragma unroll 8
        for (int k = 0; k < S_; k++) acc += Pr[wave][k] * Vs[k][lane];
        aob[(size_t)(b * S_ + r) * HID + h * DHEAD + lane] = f2bf(acc);
    }
}

__global__ __launch_bounds__(256) void ln_kernel(
    const float* __restrict__ src, const void* __restrict__ g,
    const void* __restrict__ bb, size_t goff,
    float* __restrict__ dst, unsigned short* __restrict__ dstb,
    const int* __restrict__ dtf)
{
    int isf32 = dtf[0];
    int t = blockIdx.x;
    const float* x = src + (size_t)t * HID;
    int tid = threadIdx.x, lane = tid & 63, wave = tid >> 6;
    float v0 = x[tid], v1 = x[tid + 256];
    float s = v0 + v1;
    for (int off = 32; off; off >>= 1) s += __shfl_down(s, off, 64);
    __shared__ float wsum[4];
    if (lane == 0) wsum[wave] = s;
    __syncthreads();
    float mu = (wsum[0] + wsum[1] + wsum[2] + wsum[3]) * (1.f / 512.f);
    float d0 = v0 - mu, d1 = v1 - mu;
    float q = d0 * d0 + d1 * d1;
    for (int off = 32; off; off >>= 1) q += __shfl_down(q, off, 64);
    __syncthreads();
    if (lane == 0) wsum[wave] = q;
    __syncthreads();
    float var = (wsum[0] + wsum[1] + wsum[2] + wsum[3]) * (1.f / 512.f);
    float rstd = 1.f / sqrtf(var + 1e-5f);
    float y0 = d0 * rstd * ldin(g, goff + tid, isf32)       + ldin(bb, goff + tid, isf32);
    float y1 = d1 * rstd * ldin(g, goff + tid + 256, isf32) + ldin(bb, goff + tid + 256, isf32);
    if (dst) {
        dst[(size_t)t * HID + tid]       = y0;
        dst[(size_t)t * HID + tid + 256] = y1;
    }
    if (dstb) {
        dstb[(size_t)t * HID + tid]       = f2bf(y0);
        dstb[(size_t)t * HID + tid + 256] = f2bf(y1);
    }
}

extern "C" void kernel_launch(void* const* d_in, const int* in_sizes, int n_in,
                              void* d_out, int out_size, void* d_ws, size_t ws_size,
                              hipStream_t stream)
{
    const void* x_lhand = d_in[0];
    const void* x_rhand = d_in[1];
    const void* j_lhand = d_in[2];
    const void* j_rhand = d_in[3];
    const void* m_contact = d_in[4];
    const void* x_obj = d_in[5];
    const void* point_cloud = d_in[6];
    const void* fc_lw = d_in[7];
    const void* fc_lb = d_in[8];
    const void* fc_rw = d_in[9];
    const void* fc_rb = d_in[10];
    const void* out_lw = d_in[11];
    const void* out_lb = d_in[12];
    const void* out_rw = d_in[13];
    const void* out_rb = d_in[14];
    const void* Wqkv = d_in[15];
    const void* bqkv = d_in[16];
    const void* Wo   = d_in[17];
    const void* bo   = d_in[18];
    const void* W1   = d_in[19];
    const void* b1f  = d_in[20];
    const void* W2   = d_in[21];
    const void* b2fp = d_in[22];
    const void* ln1g = d_in[23];
    const void* ln1b = d_in[24];
    const void* ln2g = d_in[25];
    const void* ln2b = d_in[26];

    float* ws = (float*)d_ws;
    int* dtf = (int*)d_ws;
    float* x     = ws + F_X;
    float* qkv   = ws + F_QKV;
    float* tmp   = ws + F_TMP;
    float* h     = ws + F_H;
    unsigned short* wb   = (unsigned short*)(ws + WB_F);
    unsigned short* catl = wb + U_CATL;
    unsigned short* catr = wb + U_CATR;
    unsigned short* xb   = wb + U_XB;
    unsigned short* aob  = wb + U_AOB;
    unsigned short* hb   = wb + U_HB;
    unsigned short* ffb  = wb + U_FFB;

    detect_kernel<<<1, 256, 0, stream>>>(m_contact, dtf);

    wtrans_kernel<<<dim3(8, 36, 1), 256, 0, stream>>>(fc_lw, 0, CATD, HID, HID, CATP, wb + W_FCL, 0, dtf);
    wtrans_kernel<<<dim3(8, 36, 1), 256, 0, stream>>>(fc_rw, 0, CATD, HID, HID, CATP, wb + W_FCR, 0, dtf);
    wtrans_kernel<<<dim3(24, 8, NLAY), 256, 0, stream>>>(Wqkv, (size_t)HID*1536, HID, 1536, 1536, HID, wb + W_QKV, (size_t)1536*HID, dtf);
    wtrans_kernel<<<dim3(8, 8, NLAY), 256, 0, stream>>>(Wo, (size_t)HID*HID, HID, HID, HID, HID, wb + W_WO, (size_t)HID*HID, dtf);
    wtrans_kernel<<<dim3(32, 8, NLAY), 256, 0, stream>>>(W1, (size_t)HID*2048, HID, 2048, 2048, HID, wb + W_W1, (size_t)2048*HID, dtf);
    wtrans_kernel<<<dim3(8, 32, NLAY), 256, 0, stream>>>(W2, (size_t)2048*HID, 2048, HID, HID, 2048, wb + W_W2, (size_t)HID*2048, dtf);
    // combined out weight: rows 0..98 = out_lw^T, 99..197 = out_rw^T, rest 0
    wtrans_kernel<<<dim3(2, 8, 1), 256, 0, stream>>>(out_lw, 0, HID, HANDD, HANDD, HID, wb + W_OUT, 0, dtf);
    wtrans_kernel<<<dim3(2, 8, 1), 256, 0, stream>>>(out_rw, 0, HID, HANDD, HANDD, HID, wb + W_OUT + (size_t)HANDD * HID, 0, dtf);

    pctcat_kernel<<<B_ * L_, 256, 0, stream>>>(
        x_lhand, j_lhand, x_rhand, j_rhand, m_contact, x_obj, point_cloud,
        catl, catr, dtf);

    // fc both hands in one dispatch: 2 x (16x8) blocks; PE fused
    gemm_ks<<<256, 256, 0, stream>>>(catl, catr, CATP, wb, W_FCL, W_FCR, 128, HID,
                                     fc_lb, fc_rb, 0, nullptr, x, xb, 0, 1, 8, dtf);

    for (int i = 0; i < NLAY; i++) {
        size_t oWq = (size_t)W_QKV + (size_t)i * 1536 * HID, obq = (size_t)i * 1536;
        size_t oWo = (size_t)W_WO + (size_t)i * HID * HID,   obo = (size_t)i * HID;
        size_t oW1 = (size_t)W_W1 + (size_t)i * 2048 * HID,  ob1 = (size_t)i * 2048;
        size_t oW2 = (size_t)W_W2 + (size_t)i * HID * 2048,  ob2 = (size_t)i * HID;
        size_t oln = (size_t)i * HID;

        gemm_ks<<<768, 256, 0, stream>>>(xb, nullptr, HID, wb, oWq, 0, 0, 1536,
                                         bqkv, nullptr, obq, nullptr, qkv, nullptr, 0, 0, 24, dtf);

        attn_fused<<<B_ * NHEAD, 256, 0, stream>>>(qkv, aob);

        gemm_ks<<<256, 256, 0, stream>>>(aob, nullptr, HID, wb, oWo, 0, 0, HID,
                                         bo, nullptr, obo, x, tmp, nullptr, 0, 0, 8, dtf);
        ln_kernel<<<T_, 256, 0, stream>>>(tmp, ln1g, ln1b, oln, h, hb, dtf);

        gemm_ks<<<1024, 256, 0, stream>>>(hb, nullptr, HID, wb, oW1, 0, 0, 2048,
                                          b1f, nullptr, ob1, nullptr, nullptr, ffb, 1, 0, 32, dtf);
        gemm_ks<<<256, 256, 0, stream>>>(ffb, nullptr, 2048, wb, oW2, 0, 0, HID,
                                         b2fp, nullptr, ob2, h, tmp, nullptr, 0, 0, 8, dtf);
        ln_kernel<<<T_, 256, 0, stream>>>(tmp, ln2g, ln2b, oln, x, xb, dtf);
    }

    // out projection: all tokens x Wcomb[256][512], parity epilogue
    gemm_ks<<<128, 256, 0, stream>>>(xb, nullptr, HID, wb, W_OUT, 0, 0, 256,
                                     out_lb, out_rb, 0, nullptr, (float*)d_out, nullptr, 0, 3, 4, dtf);
}

// Round 10
// 721.571 us; speedup vs baseline: 1.5951x; 1.5951x over previous
//
#include <hip/hip_runtime.h>
#include <hip/hip_bf16.h>

typedef __hip_bfloat16 bf16;
typedef __attribute__((ext_vector_type(8))) short short8;
typedef __attribute__((ext_vector_type(4))) float floatx4;

#define B_    16
#define L_    64
#define N_    1024
#define HANDD 99
#define Jn    21
#define HID   512
#define NLAY  4
#define NHEAD 8
#define DHEAD 64
#define CATD  2273
#define CATP  2304
#define S_    128
#define T_    2048

// float workspace offsets
#define F_X     16
#define F_QKV   1048592
#define F_TMP   6291472
#define F_H     7340048
#define WB_F    8388624
// ushort offsets from wb
#define W_FCL   0
#define W_FCR   1179648
#define W_QKV   2359296
#define W_WO    5505024
#define W_W1    6553600
#define W_W2    10747904
#define U_CATL  14942208
#define U_CATR  17301504
#define U_XB    19660800
#define U_AOB   20709376
#define U_HB    21757952
#define W_OUT   22806528
#define U_FFB   U_CATL   // alias: cat buffers dead after fc

static __device__ __forceinline__ float b2f(bf16 x) { return __bfloat162float(x); }
static __device__ __forceinline__ float ldin(const void* p, size_t i, int isf32) {
    return isf32 ? ((const float*)p)[i] : b2f(((const bf16*)p)[i]);
}
static __device__ __forceinline__ unsigned short f2bf(float f) {
    unsigned int u = __float_as_uint(f);
    unsigned int r = (u + 0x7fffu + ((u >> 16) & 1u)) >> 16;
    return (unsigned short)r;
}

__global__ __launch_bounds__(256) void detect_kernel(const void* mc, int* flag)
{
    __shared__ int sbad;
    int tid = threadIdx.x;
    if (tid == 0) sbad = 0;
    __syncthreads();
    int bad = 0;
    for (int i = tid; i < 16384; i += 256) {
        float v = b2f(((const bf16*)mc)[i]);
        if (!(v >= -0.02f && v <= 1.02f)) bad = 1;
    }
    if (bad) atomicOr(&sbad, 1);
    __syncthreads();
    if (tid == 0) flag[0] = sbad ? 1 : 0;
}

// weight transpose+convert: src [K][NnBound] -> dst [N][Kpad] bf16, zero pad
__global__ __launch_bounds__(256) void wtrans_kernel(
    const void* __restrict__ src, size_t src_layer, int K, int Nn, int NnBound,
    int Kpad, unsigned short* __restrict__ dst, size_t dst_layer,
    const int* __restrict__ dtf)
{
    int isf32 = dtf[0];
    __shared__ float tile[64][65];
    int lay = blockIdx.z;
    size_t soff = (size_t)lay * src_layer;
    size_t doff = (size_t)lay * dst_layer;
    int n0 = blockIdx.x * 64, k0 = blockIdx.y * 64;
    int a = threadIdx.x & 63, bq = threadIdx.x >> 6;
    for (int r = bq; r < 64; r += 4) {
        int k = k0 + r;
        int n = n0 + a;
        float v = (k < K && n < NnBound) ? ldin(src, soff + (size_t)k * Nn + n, isf32) : 0.f;
        tile[r][a] = v;
    }
    __syncthreads();
    for (int r = bq; r < 64; r += 4) {
        dst[doff + (size_t)(n0 + r) * Kpad + k0 + a] = f2bf(tile[a][r]);
    }
}

// fused: rot6d->R, pc transform (LDS), pcn, NN-contact attention, both hands'
// bf16 feature rows. grid B*L blocks.
__global__ __launch_bounds__(256) void pctcat_kernel(
    const void* __restrict__ x_l, const void* __restrict__ j_l,
    const void* __restrict__ x_r, const void* __restrict__ j_r,
    const void* __restrict__ mc, const void* __restrict__ x_obj,
    const void* __restrict__ pc, unsigned short* __restrict__ cat_l,
    unsigned short* __restrict__ cat_r, const int* __restrict__ dtf)
{
    __shared__ float pcl[N_ * 3];
    __shared__ float pcnl[N_];
    int isf32 = dtf[0];
    int bl = blockIdx.x;
    int b  = bl >> 6;
    int tid = threadIdx.x;

    size_t xo = (size_t)bl * 10;
    float t0 = ldin(x_obj, xo+0, isf32), t1 = ldin(x_obj, xo+1, isf32), t2 = ldin(x_obj, xo+2, isf32);
    float a1x = ldin(x_obj, xo+3, isf32), a1y = ldin(x_obj, xo+4, isf32), a1z = ldin(x_obj, xo+5, isf32);
    float a2x = ldin(x_obj, xo+6, isf32), a2y = ldin(x_obj, xo+7, isf32), a2z = ldin(x_obj, xo+8, isf32);
    float n1 = sqrtf(a1x*a1x + a1y*a1y + a1z*a1z);
    float b1x = a1x / n1, b1y = a1y / n1, b1z = a1z / n1;
    float d = b1x*a2x + b1y*a2y + b1z*a2z;
    float c2x = a2x - d*b1x, c2y = a2y - d*b1y, c2z = a2z - d*b1z;
    float n2 = sqrtf(c2x*c2x + c2y*c2y + c2z*c2z);
    float b2x = c2x / n2, b2y = c2y / n2, b2z = c2z / n2;
    float b3x = b1y*b2z - b1z*b2y;
    float b3y = b1z*b2x - b1x*b2z;
    float b3z = b1x*b2y - b1y*b2x;

    size_t pcb = (size_t)b * N_ * 3;
    for (int n = tid; n < N_; n += 256) {
        float p0 = ldin(pc, pcb + n*3+0, isf32);
        float p1 = ldin(pc, pcb + n*3+1, isf32);
        float p2 = ldin(pc, pcb + n*3+2, isf32);
        float q0 = b1x*p0 + b2x*p1 + b3x*p2 + t0;
        float q1 = b1y*p0 + b2y*p1 + b3y*p2 + t1;
        float q2 = b1z*p0 + b2z*p1 + b3z*p2 + t2;
        pcl[n*3+0] = q0; pcl[n*3+1] = q1; pcl[n*3+2] = q2;
        pcnl[n] = sqrtf(q0*q0 + q1*q1 + q2*q2);
    }
    __syncthreads();

    #pragma unroll
    for (int hand = 0; hand < 2; hand++) {
        const void* xh = hand ? x_r : x_l;
        const void* jh = hand ? j_r : j_l;
        unsigned short* row = (hand ? cat_r : cat_l) + (size_t)bl * CATP;
        for (int c = tid; c < HANDD; c += 256)  row[c]        = f2bf(ldin(xh, (size_t)bl*HANDD + c, isf32));
        for (int c = tid; c < 63;    c += 256)  row[99 + c]   = f2bf(ldin(jh, (size_t)bl*63 + c, isf32));
        for (int c = tid; c < N_;    c += 256)  row[162 + c]  = f2bf(ldin(mc, (size_t)b*N_ + c, isf32));
        for (int c = tid; c < N_;    c += 256)  row[1186 + c] = f2bf(pcnl[c]);
        for (int c = CATD + tid; c < CATP; c += 256) row[c] = 0;
    }

    int wave = tid >> 6, lane = tid & 63;
    for (int t = wave; t < 2 * Jn; t += 4) {
        int hand = t / Jn, j = t - hand * Jn;
        const void* jh = hand ? j_r : j_l;
        unsigned short* row = (hand ? cat_r : cat_l) + (size_t)bl * CATP;
        float jx = ldin(jh, (size_t)bl*63 + j*3 + 0, isf32);
        float jy = ldin(jh, (size_t)bl*63 + j*3 + 1, isf32);
        float jz = ldin(jh, (size_t)bl*63 + j*3 + 2, isf32);
        float jj = jx*jx + jy*jy + jz*jz;
        float best = 3.4e38f; int bidx = 0x7fffffff;
        for (int n = lane; n < N_; n += 64) {
            float p0 = pcl[n*3+0], p1 = pcl[n*3+1], p2 = pcl[n*3+2];
            float d2 = jj + (p0*p0 + p1*p1 + p2*p2) - 2.f*(jx*p0 + jy*p1 + jz*p2);
            if (d2 < best) { best = d2; bidx = n; }
        }
        for (int off = 32; off; off >>= 1) {
            float ob = __shfl_down(best, off, 64);
            int   oi = __shfl_down(bidx, off, 64);
            if (ob < best || (ob == best && oi < bidx)) { best = ob; bidx = oi; }
        }
        bidx = __shfl(bidx, 0, 64);
        if (lane < 3) {
            float jc = (lane == 0) ? jx : ((lane == 1) ? jy : jz);
            float cc = pcl[bidx*3 + lane];
            float dd = jc - cc;
            row[2210 + j*3 + lane] = f2bf(expf(-50.f * dd * dd));
        }
    }
}

// K-split MFMA GEMM: one 64x64 tile per block, 4 waves each take K/4,
// LDS tree-reduce. rowmap: 0 plain, 1/2 fc scatter + fused PE, 3 out-proj
// parity store. halfgrid: blocks >= halfgrid use Ab2/wtoff2/bias2 (rowmap 2).
#define RSTR 68

__global__ __launch_bounds__(256) void gemm_ks(
    const unsigned short* __restrict__ Ab, const unsigned short* __restrict__ Ab2,
    int K,
    const unsigned short* __restrict__ Wt, size_t wtoff, size_t wtoff2, int halfgrid,
    int Nn,
    const void* __restrict__ bias, const void* __restrict__ bias2, size_t boff,
    const float* __restrict__ resid,
    float* __restrict__ Df, unsigned short* __restrict__ Db,
    int relu, int rowmap, int tilesN, const int* __restrict__ dtf)
{
    __shared__ float red[4][64 * RSTR];
    int blk = blockIdx.x;
    if (halfgrid && blk >= halfgrid) {
        blk -= halfgrid; Ab = Ab2; wtoff = wtoff2; bias = bias2; rowmap = 2;
    }
    int tid = threadIdx.x;
    int wave = tid >> 6, lane = tid & 63;
    int quad = lane >> 4, l16 = lane & 15;
    int tm = blk / tilesN, tn = blk - tm * tilesN;
    int row0 = tm << 6, col0 = tn << 6;
    int Ks = K >> 2;
    int ks0 = wave * Ks;

    const unsigned short* Ap = Ab + (size_t)(row0 + l16) * K + ks0 + quad * 8;
    const unsigned short* Bp = Wt + wtoff + (size_t)(col0 + l16) * K + ks0 + quad * 8;
    size_t astep = (size_t)16 * K;

    floatx4 acc[4][4];
    #pragma unroll
    for (int i = 0; i < 4; i++)
        #pragma unroll
        for (int j = 0; j < 4; j++)
            acc[i][j] = (floatx4){0.f, 0.f, 0.f, 0.f};

    for (int k = 0; k < Ks; k += 32) {
        short8 af[4], bf[4];
        #pragma unroll
        for (int i = 0; i < 4; i++) {
            af[i] = *(const short8*)(Ap + i * astep + k);
            bf[i] = *(const short8*)(Bp + i * astep + k);
        }
        #pragma unroll
        for (int mi = 0; mi < 4; mi++)
            #pragma unroll
            for (int ni = 0; ni < 4; ni++)
                acc[mi][ni] = __builtin_amdgcn_mfma_f32_16x16x32_bf16(
                    af[mi], bf[ni], acc[mi][ni], 0, 0, 0);
    }

    #pragma unroll
    for (int mi = 0; mi < 4; mi++)
        #pragma unroll
        for (int ni = 0; ni < 4; ni++)
            #pragma unroll
            for (int reg = 0; reg < 4; reg++) {
                int r = mi * 16 + quad * 4 + reg;
                int c = ni * 16 + l16;
                red[wave][r * RSTR + c] = acc[mi][ni][reg];
            }
    __syncthreads();

    int isf32 = dtf[0];
    int cc = tid & 63;
    int c = col0 + cc;
    float bv;
    if (rowmap == 3)
        bv = (c < HANDD) ? ldin(bias, c, isf32)
           : ((c < 2 * HANDD) ? ldin(bias2, c - HANDD, isf32) : 0.f);
    else
        bv = bias ? ldin(bias, boff + c, isf32) : 0.f;
    float pe_div = 0.f, pa = 0.f;
    if (rowmap == 1 || rowmap == 2) {
        int ci = c & ~1;
        pe_div = expf((float)ci * (-logf(10000.f) / (float)HID));
        int hand = rowmap - 1;
        pa = (c & 1) ? cosf((float)hand * pe_div) : sinf((float)hand * pe_div);
    }
    int rbase = tid >> 6;
    #pragma unroll
    for (int j = 0; j < 16; j++) {
        int rr = rbase + (j << 2);
        int idx = rr * RSTR + cc;
        float v = red[0][idx] + red[1][idx] + red[2][idx] + red[3][idx] + bv;
        int r = row0 + rr;
        if (resid) v += resid[(size_t)r * Nn + c];
        if (relu)  v = fmaxf(v, 0.f);
        if (rowmap == 3) {
            int hand = r & 1;
            int l = (r >> 1) & 63, bb = r >> 7;
            if (hand == 0 && c < HANDD) {
                size_t oi = ((size_t)bb * 64 + l) * HANDD + c;
                if (isf32) ((float*)Df)[oi] = v;
                else       ((bf16*)Df)[oi]  = __float2bfloat16(v);
            } else if (hand == 1 && c >= HANDD && c < 2 * HANDD) {
                size_t oi = (size_t)B_ * L_ * HANDD + ((size_t)bb * 64 + l) * HANDD + (c - HANDD);
                if (isf32) ((float*)Df)[oi] = v;
                else       ((bf16*)Df)[oi]  = __float2bfloat16(v);
            }
        } else {
            int orow = r;
            if (rowmap) {
                int bb = r >> 6, ll = r & 63;
                orow = bb * S_ + 2 * ll + (rowmap - 1);
                float pf = (c & 1) ? cosf((float)ll * pe_div) : sinf((float)ll * pe_div);
                v += pf + pa;
            }
            if (Df) Df[(size_t)orow * Nn + c] = v;
            if (Db) Db[(size_t)orow * Nn + c] = f2bf(v);
        }
    }
}

// MFMA attention: one (b,h) per blockIdx.x, row-half per blockIdx.y.
// QK^T and PV via mfma_16x16x32_bf16; softmax on C-layout frags;
// P LDS round-trip (C-layout -> A-layout); V^T staged in LDS.
#define VSTR 136

__global__ __launch_bounds__(128) void attn_mfma(
    const unsigned short* __restrict__ qkvb, unsigned short* __restrict__ aob)
{
    __shared__ unsigned short Vt[64 * VSTR];
    __shared__ unsigned short Pb[64 * VSTR];
    int bh = blockIdx.x;
    int b = bh >> 3, h = bh & 7;
    int rowhalf = blockIdx.y;
    int tid = threadIdx.x;
    int w = tid >> 6, lane = tid & 63;
    int quad = lane >> 4, l16 = lane & 15;
    size_t qbase = (size_t)(b * S_) * 1536 + h * DHEAD;

    // stage V^T: Vt[dcol][key]
    for (int i = tid; i < S_ * DHEAD; i += 128) {
        int key = i >> 6, dcol = i & 63;
        Vt[dcol * VSTR + key] = qkvb[qbase + (size_t)key * 1536 + 1024 + dcol];
    }
    __syncthreads();

    int qrow0 = rowhalf * 64 + w * 32;
    // Q A-frags (2 m-tiles x 2 k-chunks)
    short8 aQ[2][2];
    #pragma unroll
    for (int mt = 0; mt < 2; mt++)
        #pragma unroll
        for (int kc = 0; kc < 2; kc++)
            aQ[mt][kc] = *(const short8*)&qkvb[qbase + (size_t)(qrow0 + mt*16 + l16) * 1536 + kc*32 + quad*8];

    floatx4 sacc[2][8];
    #pragma unroll
    for (int mt = 0; mt < 2; mt++)
        #pragma unroll
        for (int nt = 0; nt < 8; nt++)
            sacc[mt][nt] = (floatx4){0.f, 0.f, 0.f, 0.f};

    #pragma unroll
    for (int nt = 0; nt < 8; nt++) {
        const unsigned short* kp = &qkvb[qbase + (size_t)(nt*16 + l16) * 1536 + 512 + quad*8];
        short8 bK0 = *(const short8*)kp;
        short8 bK1 = *(const short8*)(kp + 32);
        #pragma unroll
        for (int mt = 0; mt < 2; mt++) {
            sacc[mt][nt] = __builtin_amdgcn_mfma_f32_16x16x32_bf16(aQ[mt][0], bK0, sacc[mt][nt], 0, 0, 0);
            sacc[mt][nt] = __builtin_amdgcn_mfma_f32_16x16x32_bf16(aQ[mt][1], bK1, sacc[mt][nt], 0, 0, 0);
        }
    }

    // softmax per row (row = quad*4+reg within m-tile; cols spread over nt,l16)
    #pragma unroll
    for (int mt = 0; mt < 2; mt++)
        #pragma unroll
        for (int reg = 0; reg < 4; reg++) {
            float v[8];
            float m = -3.4e38f;
            #pragma unroll
            for (int nt = 0; nt < 8; nt++) { v[nt] = sacc[mt][nt][reg] * 0.125f; m = fmaxf(m, v[nt]); }
            #pragma unroll
            for (int off = 1; off <= 8; off <<= 1) m = fmaxf(m, __shfl_xor(m, off, 64));
            float sum = 0.f;
            #pragma unroll
            for (int nt = 0; nt < 8; nt++) { v[nt] = expf(v[nt] - m); sum += v[nt]; }
            #pragma unroll
            for (int off = 1; off <= 8; off <<= 1) sum += __shfl_xor(sum, off, 64);
            float inv = 1.f / sum;
            int lr = w*32 + mt*16 + quad*4 + reg;
            #pragma unroll
            for (int nt = 0; nt < 8; nt++)
                Pb[lr * VSTR + nt*16 + l16] = f2bf(v[nt] * inv);
        }
    __syncthreads();

    // PV: A = P (A-layout), B = V^T
    #pragma unroll
    for (int mt = 0; mt < 2; mt++) {
        short8 aP[4];
        #pragma unroll
        for (int kt = 0; kt < 4; kt++)
            aP[kt] = *(const short8*)&Pb[(w*32 + mt*16 + l16) * VSTR + kt*32 + quad*8];
        #pragma unroll
        for (int nt = 0; nt < 4; nt++) {
            floatx4 o = (floatx4){0.f, 0.f, 0.f, 0.f};
            #pragma unroll
            for (int kt = 0; kt < 4; kt++) {
                short8 bV = *(const short8*)&Vt[(nt*16 + l16) * VSTR + kt*32 + quad*8];
                o = __builtin_amdgcn_mfma_f32_16x16x32_bf16(aP[kt], bV, o, 0, 0, 0);
            }
            #pragma unroll
            for (int reg = 0; reg < 4; reg++) {
                int qrow = qrow0 + mt*16 + quad*4 + reg;
                aob[(size_t)(b*S_ + qrow) * HID + h*DHEAD + nt*16 + l16] = f2bf(o[reg]);
            }
        }
    }
}

__global__ __launch_bounds__(256) void ln_kernel(
    const float* __restrict__ src, const void* __restrict__ g,
    const void* __restrict__ bb, size_t goff,
    float* __restrict__ dst, unsigned short* __restrict__ dstb,
    const int* __restrict__ dtf)
{
    int isf32 = dtf[0];
    int t = blockIdx.x;
    const float* x = src + (size_t)t * HID;
    int tid = threadIdx.x, lane = tid & 63, wave = tid >> 6;
    float v0 = x[tid], v1 = x[tid + 256];
    float s = v0 + v1;
    for (int off = 32; off; off >>= 1) s += __shfl_down(s, off, 64);
    __shared__ float wsum[4];
    if (lane == 0) wsum[wave] = s;
    __syncthreads();
    float mu = (wsum[0] + wsum[1] + wsum[2] + wsum[3]) * (1.f / 512.f);
    float d0 = v0 - mu, d1 = v1 - mu;
    float q = d0 * d0 + d1 * d1;
    for (int off = 32; off; off >>= 1) q += __shfl_down(q, off, 64);
    __syncthreads();
    if (lane == 0) wsum[wave] = q;
    __syncthreads();
    float var = (wsum[0] + wsum[1] + wsum[2] + wsum[3]) * (1.f / 512.f);
    float rstd = 1.f / sqrtf(var + 1e-5f);
    float y0 = d0 * rstd * ldin(g, goff + tid, isf32)       + ldin(bb, goff + tid, isf32);
    float y1 = d1 * rstd * ldin(g, goff + tid + 256, isf32) + ldin(bb, goff + tid + 256, isf32);
    if (dst) {
        dst[(size_t)t * HID + tid]       = y0;
        dst[(size_t)t * HID + tid + 256] = y1;
    }
    if (dstb) {
        dstb[(size_t)t * HID + tid]       = f2bf(y0);
        dstb[(size_t)t * HID + tid + 256] = f2bf(y1);
    }
}

extern "C" void kernel_launch(void* const* d_in, const int* in_sizes, int n_in,
                              void* d_out, int out_size, void* d_ws, size_t ws_size,
                              hipStream_t stream)
{
    const void* x_lhand = d_in[0];
    const void* x_rhand = d_in[1];
    const void* j_lhand = d_in[2];
    const void* j_rhand = d_in[3];
    const void* m_contact = d_in[4];
    const void* x_obj = d_in[5];
    const void* point_cloud = d_in[6];
    const void* fc_lw = d_in[7];
    const void* fc_lb = d_in[8];
    const void* fc_rw = d_in[9];
    const void* fc_rb = d_in[10];
    const void* out_lw = d_in[11];
    const void* out_lb = d_in[12];
    const void* out_rw = d_in[13];
    const void* out_rb = d_in[14];
    const void* Wqkv = d_in[15];
    const void* bqkv = d_in[16];
    const void* Wo   = d_in[17];
    const void* bo   = d_in[18];
    const void* W1   = d_in[19];
    const void* b1f  = d_in[20];
    const void* W2   = d_in[21];
    const void* b2fp = d_in[22];
    const void* ln1g = d_in[23];
    const void* ln1b = d_in[24];
    const void* ln2g = d_in[25];
    const void* ln2b = d_in[26];

    float* ws = (float*)d_ws;
    int* dtf = (int*)d_ws;
    float* x     = ws + F_X;
    float* tmp   = ws + F_TMP;
    float* h     = ws + F_H;
    unsigned short* qkvb = (unsigned short*)(ws + F_QKV);
    unsigned short* wb   = (unsigned short*)(ws + WB_F);
    unsigned short* catl = wb + U_CATL;
    unsigned short* catr = wb + U_CATR;
    unsigned short* xb   = wb + U_XB;
    unsigned short* aob  = wb + U_AOB;
    unsigned short* hb   = wb + U_HB;
    unsigned short* ffb  = wb + U_FFB;

    detect_kernel<<<1, 256, 0, stream>>>(m_contact, dtf);

    wtrans_kernel<<<dim3(8, 36, 1), 256, 0, stream>>>(fc_lw, 0, CATD, HID, HID, CATP, wb + W_FCL, 0, dtf);
    wtrans_kernel<<<dim3(8, 36, 1), 256, 0, stream>>>(fc_rw, 0, CATD, HID, HID, CATP, wb + W_FCR, 0, dtf);
    wtrans_kernel<<<dim3(24, 8, NLAY), 256, 0, stream>>>(Wqkv, (size_t)HID*1536, HID, 1536, 1536, HID, wb + W_QKV, (size_t)1536*HID, dtf);
    wtrans_kernel<<<dim3(8, 8, NLAY), 256, 0, stream>>>(Wo, (size_t)HID*HID, HID, HID, HID, HID, wb + W_WO, (size_t)HID*HID, dtf);
    wtrans_kernel<<<dim3(32, 8, NLAY), 256, 0, stream>>>(W1, (size_t)HID*2048, HID, 2048, 2048, HID, wb + W_W1, (size_t)2048*HID, dtf);
    wtrans_kernel<<<dim3(8, 32, NLAY), 256, 0, stream>>>(W2, (size_t)2048*HID, 2048, HID, HID, 2048, wb + W_W2, (size_t)HID*2048, dtf);
    wtrans_kernel<<<dim3(2, 8, 1), 256, 0, stream>>>(out_lw, 0, HID, HANDD, HANDD, HID, wb + W_OUT, 0, dtf);
    wtrans_kernel<<<dim3(2, 8, 1), 256, 0, stream>>>(out_rw, 0, HID, HANDD, HANDD, HID, wb + W_OUT + (size_t)HANDD * HID, 0, dtf);

    pctcat_kernel<<<B_ * L_, 256, 0, stream>>>(
        x_lhand, j_lhand, x_rhand, j_rhand, m_contact, x_obj, point_cloud,
        catl, catr, dtf);

    // fc both hands in one dispatch: 2 x (16x8) blocks; PE fused
    gemm_ks<<<256, 256, 0, stream>>>(catl, catr, CATP, wb, W_FCL, W_FCR, 128, HID,
                                     fc_lb, fc_rb, 0, nullptr, x, xb, 0, 1, 8, dtf);

    for (int i = 0; i < NLAY; i++) {
        size_t oWq = (size_t)W_QKV + (size_t)i * 1536 * HID, obq = (size_t)i * 1536;
        size_t oWo = (size_t)W_WO + (size_t)i * HID * HID,   obo = (size_t)i * HID;
        size_t oW1 = (size_t)W_W1 + (size_t)i * 2048 * HID,  ob1 = (size_t)i * 2048;
        size_t oW2 = (size_t)W_W2 + (size_t)i * HID * 2048,  ob2 = (size_t)i * HID;
        size_t oln = (size_t)i * HID;

        // qkv: bf16 output only (consumed by MFMA attention)
        gemm_ks<<<768, 256, 0, stream>>>(xb, nullptr, HID, wb, oWq, 0, 0, 1536,
                                         bqkv, nullptr, obq, nullptr, nullptr, qkvb, 0, 0, 24, dtf);

        attn_mfma<<<dim3(B_ * NHEAD, 2), 128, 0, stream>>>(qkvb, aob);

        gemm_ks<<<256, 256, 0, stream>>>(aob, nullptr, HID, wb, oWo, 0, 0, HID,
                                         bo, nullptr, obo, x, tmp, nullptr, 0, 0, 8, dtf);
        ln_kernel<<<T_, 256, 0, stream>>>(tmp, ln1g, ln1b, oln, h, hb, dtf);

        gemm_ks<<<1024, 256, 0, stream>>>(hb, nullptr, HID, wb, oW1, 0, 0, 2048,
                                          b1f, nullptr, ob1, nullptr, nullptr, ffb, 1, 0, 32, dtf);
        gemm_ks<<<256, 256, 0, stream>>>(ffb, nullptr, 2048, wb, oW2, 0, 0, HID,
                                         b2fp, nullptr, ob2, h, tmp, nullptr, 0, 0, 8, dtf);
        ln_kernel<<<T_, 256, 0, stream>>>(tmp, ln2g, ln2b, oln, x, xb, dtf);
    }

    // out projection: all tokens x Wcomb[256][512], parity epilogue
    gemm_ks<<<128, 256, 0, stream>>>(xb, nullptr, HID, wb, W_OUT, 0, 0, 256,
                                     out_lb, out_rb, 0, nullptr, (float*)d_out, nullptr, 0, 3, 4, dtf);
}